// Round 7
// baseline (131.953 us; speedup 1.0000x reference)
//
#include <hip/hip_runtime.h>

// CORN loss: logits [B, K-1] fp32, targets [B] int (1..K), out = mean loss (fp32 scalar)
// B = 4194304, K = 10 -> 9 logits/row, 37,748,736 terms = 9,437,184 float4s.
// loss(x, bt) = -log(sigmoid(bt ? x : -x) + 1e-7) ~= log(1 + exp(bt ? -x : x))
// Log batching: sum_k log(1+e^sk) = log prod_k (1+e^sk) per float4.
//
// Tail fusion v2: per-block RELAXED native f32 atomic (global_atomic_add_f32,
// no L2 cacheops -- round 5's 13x regression was the ORDERED ticket atomics'
// buffer_wbl2/inv per block, not atomics per se; guide G12 endorses one relaxed
// atomic per block). d_out zeroed per call by a 4-byte memset node, since the
// harness does not re-poison d_out between graph replays.

#define BATCH    4194304
#define KM1      9

constexpr int THREADS = 256;
constexpr int F4_PER_THREAD = 4;
constexpr int BLOCKS = (BATCH * KM1 / 4) / (THREADS * F4_PER_THREAD);  // 9216

typedef __attribute__((ext_vector_type(4))) float f32x4;

__global__ __launch_bounds__(THREADS) void corn_fused_kernel(
    const float* __restrict__ logits,
    const int*   __restrict__ targets,
    float*       __restrict__ out) {
    const unsigned q0 = blockIdx.x * (THREADS * F4_PER_THREAD) + threadIdx.x;

    // 4 coalesced logits loads issued up-front (lane stride 16 B -> 4 KB/wave-instr)
    f32x4 v[F4_PER_THREAD];
    #pragma unroll
    for (int j = 0; j < F4_PER_THREAD; ++j)
        v[j] = reinterpret_cast<const f32x4*>(logits)[q0 + j * THREADS];

    // Per-float4 row/rank bookkeeping (targets near-coalesced, L1/L2-served)
    int rk0[F4_PER_THREAD], rk1[F4_PER_THREAD], kk0[F4_PER_THREAD];
    #pragma unroll
    for (int j = 0; j < F4_PER_THREAD; ++j) {
        const unsigned e0  = (q0 + j * THREADS) * 4u;
        const unsigned row = e0 / 9u;                   // magic-mul div
        kk0[j] = (int)(e0 - 9u * row);
        const unsigned r1 = (row + 1u < BATCH) ? row + 1u : (BATCH - 1u);
        rk0[j] = targets[row] - 1;
        rk1[j] = targets[r1]  - 1;
    }

    float acc = 0.0f;
    #pragma unroll
    for (int j = 0; j < F4_PER_THREAD; ++j) {
        const float* f = reinterpret_cast<const float*>(&v[j]);
        float prod = 1.0f;
        #pragma unroll
        for (int c = 0; c < 4; ++c) {
            const int  k  = kk0[j] + c;
            const bool nx = (k >= 9);
            const int  kk = nx ? k - 9 : k;
            const int  rk = nx ? rk1[j] : rk0[j];
            const float x = f[c];
            const float s = (kk < rk) ? -x : x;   // bt=1 -> e^-x, bt=0 -> e^x
            prod *= 1.0f + __expf(s);             // 4 indep exps, short mul chain
        }
        acc += __logf(prod);                      // 1 log per 4 elements
    }

    // wave (64-lane) butterfly reduce
    #pragma unroll
    for (int off = 32; off > 0; off >>= 1)
        acc += __shfl_down(acc, off, 64);

    __shared__ float smem[THREADS / 64];
    if ((threadIdx.x & 63) == 0) smem[threadIdx.x >> 6] = acc;
    __syncthreads();
    if (threadIdx.x == 0) {
        const float inv_n = 1.0f / 37748736.0f;  // 1/(B*(K-1)), exact
        const float s = (smem[0] + smem[1] + smem[2] + smem[3]) * inv_n;
        // Relaxed device-scope native f32 atomic: no cacheops, one per block.
        unsafeAtomicAdd(out, s);
    }
}

extern "C" void kernel_launch(void* const* d_in, const int* in_sizes, int n_in,
                              void* d_out, int out_size, void* d_ws, size_t ws_size,
                              hipStream_t stream) {
    const float* logits  = (const float*)d_in[0];
    const int*   targets = (const int*)d_in[1];
    float*       out     = (float*)d_out;

    // d_out must start at 0 every call (atomic accumulation; harness does not
    // re-poison between replays). 4-byte stream-ordered memset, capture-safe.
    hipMemsetAsync(out, 0, sizeof(float), stream);
    corn_fused_kernel<<<BLOCKS, THREADS, 0, stream>>>(logits, targets, out);
}

// Round 8
// 32.569 us; speedup vs baseline: 4.0515x; 4.0515x over previous
//
#include <hip/hip_runtime.h>

// CORN loss: logits [B, K-1] fp32, targets [B] int (1..K), out = mean loss (fp32 scalar)
// B = 4194304, K = 10 -> 9 logits/row, 37,748,736 terms = 9,437,184 float4s.
// loss(x, bt) = -log(sigmoid(bt ? x : -x) + 1e-7) ~= log(1 + exp(bt ? -x : x))
// Log batching: sum_k log(1+e^sk) = log prod_k (1+e^sk) per float4.
//
// Round-7 lessons: (a) single-address atomics serialize ~10ns/op at the
// coherent point regardless of scope ordering -> two-kernel tail, no atomics.
// (b) Timed replays are L3-warm (FETCH~0) -> floor is LLC BW (~10-17us), not
// HBM. (c) VGPR=20 proved the compiler serialized the "in-flight" loads.
// This round: F4T=8, all loads issued first, __launch_bounds__(256,4) to give
// the allocator 128 VGPRs so 8 float4s stay live -> real 8-deep MLP per wave.

#define BATCH    4194304
#define KM1      9

constexpr int THREADS = 256;
constexpr int F4T     = 8;
constexpr unsigned TOTAL_F4 = (unsigned)BATCH * KM1 / 4;   // 9,437,184
constexpr int BLOCKS = TOTAL_F4 / (THREADS * F4T);         // 4608

typedef __attribute__((ext_vector_type(4))) float f32x4;

__global__ __launch_bounds__(THREADS, 4) void corn_partial_kernel(
    const float* __restrict__ logits,
    const int*   __restrict__ targets,
    float*       __restrict__ partials) {
    const unsigned q0 = blockIdx.x * (unsigned)(THREADS * F4T) + threadIdx.x;

    // All 8 coalesced loads issued before ANY dependent work
    // (lane stride 16 B -> 4 KB per wave instruction).
    f32x4 v[F4T];
    #pragma unroll
    for (int j = 0; j < F4T; ++j)
        v[j] = reinterpret_cast<const f32x4*>(logits)[q0 + j * THREADS];

    // Per-float4 row/rank bookkeeping (targets near-coalesced, L1-served);
    // independent of v[] -> overlaps the logits-load latency.
    int rk0[F4T], rk1[F4T], kk0[F4T];
    #pragma unroll
    for (int j = 0; j < F4T; ++j) {
        const unsigned e0  = (q0 + j * THREADS) * 4u;
        const unsigned row = e0 / 9u;                   // magic-mul div
        kk0[j] = (int)(e0 - 9u * row);
        const unsigned r1  = (row + 1u < BATCH) ? row + 1u : (BATCH - 1u);
        rk0[j] = targets[row] - 1;
        rk1[j] = targets[r1]  - 1;
    }

    float acc = 0.0f;
    #pragma unroll
    for (int j = 0; j < F4T; ++j) {
        const float* f = reinterpret_cast<const float*>(&v[j]);
        float prod = 1.0f;
        #pragma unroll
        for (int c = 0; c < 4; ++c) {
            const int  k  = kk0[j] + c;
            const bool nx = (k >= 9);
            const int  kk = nx ? k - 9 : k;
            const int  rk = nx ? rk1[j] : rk0[j];
            const float x = f[c];
            const float s = (kk < rk) ? -x : x;   // bt=1 -> e^-x, bt=0 -> e^x
            prod *= 1.0f + __expf(s);             // 4 indep exps, short mul chain
        }
        acc += __logf(prod);                      // 1 log per 4 elements
    }

    // wave (64-lane) butterfly reduce
    #pragma unroll
    for (int off = 32; off > 0; off >>= 1)
        acc += __shfl_down(acc, off, 64);

    __shared__ float smem[THREADS / 64];
    if ((threadIdx.x & 63) == 0) smem[threadIdx.x >> 6] = acc;
    __syncthreads();
    if (threadIdx.x == 0)
        partials[blockIdx.x] = smem[0] + smem[1] + smem[2] + smem[3];
}

__global__ __launch_bounds__(256) void corn_final_kernel(
    const float* __restrict__ partials,
    float*       __restrict__ out) {
    float acc = 0.0f;
    #pragma unroll
    for (int i = 0; i < BLOCKS / 256; ++i)       // 18 coalesced rounds
        acc += partials[i * 256 + threadIdx.x];

    #pragma unroll
    for (int off = 32; off > 0; off >>= 1)
        acc += __shfl_down(acc, off, 64);

    __shared__ float smem[4];
    if ((threadIdx.x & 63) == 0) smem[threadIdx.x >> 6] = acc;
    __syncthreads();
    if (threadIdx.x == 0) {
        const float inv_n = 1.0f / 37748736.0f;  // 1/(B*(K-1)), exact
        out[0] = (smem[0] + smem[1] + smem[2] + smem[3]) * inv_n;
    }
}

extern "C" void kernel_launch(void* const* d_in, const int* in_sizes, int n_in,
                              void* d_out, int out_size, void* d_ws, size_t ws_size,
                              hipStream_t stream) {
    const float* logits   = (const float*)d_in[0];
    const int*   targets  = (const int*)d_in[1];
    float*       out      = (float*)d_out;
    float*       partials = (float*)d_ws;  // 4608 floats = 18 KB scratch

    corn_partial_kernel<<<BLOCKS, THREADS, 0, stream>>>(logits, targets, partials);
    corn_final_kernel<<<1, 256, 0, stream>>>(partials, out);
}